// Round 9
// baseline (4709.561 us; speedup 1.0000x reference)
//
#include <hip/hip_runtime.h>
#include <hip/hip_bf16.h>

typedef __bf16  bf16_8 __attribute__((ext_vector_type(8)));
typedef short   s16_8  __attribute__((ext_vector_type(8)));
typedef float   f32_4  __attribute__((ext_vector_type(4)));

#define T_ 512

// Issue 8 global_load_dwordx4 (one mt group: frag i=0..7, stride 1024B) from
// base b0 (i=0..3) and b0+4096 (i=4..7). No wait — caller waits via VMWAIT.
// Early-clobber outputs: must not alias the base-address registers.
#define LD8(d0,d1,d2,d3,d4,d5,d6,d7, BASE)                                  \
  { unsigned long long _b0 = (BASE), _b1 = (BASE) + 4096ull;                \
    asm volatile(                                                           \
      "global_load_dwordx4 %0, %8, off\n\t"                                 \
      "global_load_dwordx4 %1, %8, off offset:1024\n\t"                     \
      "global_load_dwordx4 %2, %8, off offset:2048\n\t"                     \
      "global_load_dwordx4 %3, %8, off offset:3072\n\t"                     \
      "global_load_dwordx4 %4, %9, off\n\t"                                 \
      "global_load_dwordx4 %5, %9, off offset:1024\n\t"                     \
      "global_load_dwordx4 %6, %9, off offset:2048\n\t"                     \
      "global_load_dwordx4 %7, %9, off offset:3072\n\t"                     \
      : "=&v"(d0),"=&v"(d1),"=&v"(d2),"=&v"(d3),                            \
        "=&v"(d4),"=&v"(d5),"=&v"(d6),"=&v"(d7)                             \
      : "v"(_b0), "v"(_b1)); }

#define LD32(AF, BASE)                                                      \
  LD8(AF[0][0],AF[0][1],AF[0][2],AF[0][3],AF[0][4],AF[0][5],AF[0][6],AF[0][7], (BASE));          \
  LD8(AF[1][0],AF[1][1],AF[1][2],AF[1][3],AF[1][4],AF[1][5],AF[1][6],AF[1][7], (BASE)+32768ull); \
  LD8(AF[2][0],AF[2][1],AF[2][2],AF[2][3],AF[2][4],AF[2][5],AF[2][6],AF[2][7], (BASE)+65536ull); \
  LD8(AF[3][0],AF[3][1],AF[3][2],AF[3][3],AF[3][4],AF[3][5],AF[3][6],AF[3][7], (BASE)+98304ull);

// Wait for all loads, then fence the scheduler so no af-consumer (MFMA is
// register-only, NOT ordered by the "memory" clobber) hoists above it.
#define VMWAIT_FENCE                                                        \
  asm volatile("s_waitcnt vmcnt(0)" ::: "memory");                          \
  __builtin_amdgcn_sched_barrier(0)

// ---------------- P1: X fp32 [T][B][1024] -> xfrag bf16 [T][4 mt][32 kc][64 lane][8]
__global__ __launch_bounds__(256) void p1_xfrag(const float* __restrict__ X,
                                                bf16_8* __restrict__ xf) {
  size_t n = (size_t)blockIdx.x * 256 + threadIdx.x;   // 4,194,304 total
  int lane = (int)(n & 63);
  int kc   = (int)((n >> 6) & 31);
  int mt   = (int)((n >> 11) & 3);
  int t    = (int)(n >> 13);
  int b  = 16 * mt + (lane & 15);
  int i0 = 32 * kc + (lane >> 4) * 8;
  const float4* ps = (const float4*)(X + ((size_t)t * 64 + b) * 1024 + i0);
  float4 a = ps[0], c = ps[1];
  bf16_8 v;
  v[0]=(__bf16)a.x; v[1]=(__bf16)a.y; v[2]=(__bf16)a.z; v[3]=(__bf16)a.w;
  v[4]=(__bf16)c.x; v[5]=(__bf16)c.y; v[6]=(__bf16)c.z; v[7]=(__bf16)c.w;
  xf[n] = v;
}

// ---------------- P2: Wi,Wh fp32 -> wfrag bf16 [256 cu][64 kc][64 lane][8]
__global__ __launch_bounds__(256) void p2_wfrag(const float* __restrict__ Wi,
                                                const float* __restrict__ Wh,
                                                bf16_8* __restrict__ wf) {
  size_t n = (size_t)blockIdx.x * 256 + threadIdx.x;   // 1,048,576 total
  int lane = (int)(n & 63);
  int kc   = (int)((n >> 6) & 63);
  int cu   = (int)(n >> 12);
  int n16 = lane & 15;
  int g  = n16 >> 2;
  int jj = n16 & 3;
  int col = 4 * cu + jj;
  int k = 32 * kc + (lane >> 4) * 8;
  const float* src = (k < 1024)
      ? (Wi + ((size_t)g * 1024 + col) * 1024 + k)
      : (Wh + ((size_t)g * 1024 + col) * 1024 + (k - 1024));
  const float4* ps = (const float4*)src;
  float4 a = ps[0], c = ps[1];
  bf16_8 v;
  v[0]=(__bf16)a.x; v[1]=(__bf16)a.y; v[2]=(__bf16)a.z; v[3]=(__bf16)a.w;
  v[4]=(__bf16)c.x; v[5]=(__bf16)c.y; v[6]=(__bf16)c.z; v[7]=(__bf16)c.w;
  wf[n] = v;
}

// ---------------- persistent LSTM: 256 blocks x 512 threads (8 waves)
// Phase A: h-waves (4-7) h-GEMM(t).
// Phase B: elementwise on h-waves.
// Phase C: x-waves (0-3) x-GEMM(t+1); wave4 publish h + stamp[cu]=t+1;
//          wave6 polls ALL 256 stamps directly (no RMW, no relay, no sleep).
__global__ __launch_bounds__(512, 2) void lstm_persist(
    const float* __restrict__ bi, const float* __restrict__ bh,
    const s16_8* __restrict__ xfrag, const s16_8* __restrict__ wfrag,
    s16_8* __restrict__ hfrag, float* __restrict__ out,
    unsigned int* __restrict__ ctr)
{
  __shared__ float gx[2][4][64][17];   // x-partials, double-buffered  34,816 B
  __shared__ float gh[4][64][17];      // h-partials                   17,408 B
  __shared__ float hvals[4][64];       // h gather for pack             1,024 B

  const int tid  = threadIdx.x;
  const int cu   = blockIdx.x;
  const int wv   = tid >> 6;
  const int lane = tid & 63;
  const bool ish = (wv >= 4);
  const unsigned long long lofs = (unsigned long long)(((wv & 3) * 8) * 1024 + lane * 16);

  // resident B-fragments of W (registers): 16 rows (4 cols x 4 gates) per CU
  s16_8 wf[8];
#pragma unroll
  for (int i = 0; i < 8; ++i)
    wf[i] = wfrag[((size_t)cu * 64 + wv * 8 + i) * 64 + lane];
#pragma unroll
  for (int i = 0; i < 8; ++i)
    asm volatile("" : "+v"(wf[i]));    // pin resident: no remat/re-load per step

  // elementwise identity (threads 256..511): eb = batch, ejj = column-in-block
  const int et  = tid - 256;
  const int eb  = et & 63;
  const int ejj = (et >> 6) & 3;
  const int j   = cu * 4 + ejj;
  float bias4[4] = {0.f, 0.f, 0.f, 0.f};
  if (tid >= 256) {
#pragma unroll
    for (int g = 0; g < 4; ++g) bias4[g] = bi[g * 1024 + j] + bh[g * 1024 + j];
  }
  float cst = 0.f, hval = 0.f;

  // stamp vector: ctr[0..255], stamp[cu] = last step this CU published
  unsigned int* stamps = ctr;

  // ---- prologue: x-waves compute gx(0)
  if (!ish) {
    s16_8 af[4][8];
    LD32(af, (unsigned long long)(const char*)xfrag + lofs);
    VMWAIT_FENCE;
    f32_4 acc[4];
#pragma unroll
    for (int mt = 0; mt < 4; ++mt) { f32_4 z = {0.f,0.f,0.f,0.f}; acc[mt] = z; }
#pragma unroll
    for (int i = 0; i < 8; ++i)
#pragma unroll
      for (int mt = 0; mt < 4; ++mt)
        acc[mt] = __builtin_amdgcn_mfma_f32_16x16x32_bf16(af[mt][i], wf[i], acc[mt], 0, 0, 0);
#pragma unroll
    for (int mt = 0; mt < 4; ++mt)
#pragma unroll
      for (int r = 0; r < 4; ++r)
        gx[0][wv][mt * 16 + (lane >> 4) * 4 + r][lane & 15] = acc[mt][r];
  }
  __syncthreads();

  for (int t = 0; t < T_; ++t) {
    // ---- phase A: h-waves GEMM h(t-1) — sole user of the L2 pull window
    if (ish) {
      s16_8 af[4][8];
      LD32(af, (unsigned long long)((const char*)hfrag + (size_t)(t & 1) * 131072) + lofs);
      VMWAIT_FENCE;
      f32_4 acc[4];
#pragma unroll
      for (int mt = 0; mt < 4; ++mt) { f32_4 z = {0.f,0.f,0.f,0.f}; acc[mt] = z; }
#pragma unroll
      for (int i = 0; i < 8; ++i)
#pragma unroll
        for (int mt = 0; mt < 4; ++mt)
          acc[mt] = __builtin_amdgcn_mfma_f32_16x16x32_bf16(af[mt][i], wf[i], acc[mt], 0, 0, 0);
#pragma unroll
      for (int mt = 0; mt < 4; ++mt)
#pragma unroll
        for (int r = 0; r < 4; ++r)
          gh[wv & 3][mt * 16 + (lane >> 4) * 4 + r][lane & 15] = acc[mt][r];
    }
    __syncthreads();

    // ---- phase B: elementwise cell update on h-waves (threads 256..511)
    if (tid >= 256) {
      const int xb = t & 1;
      float g4[4];
#pragma unroll
      for (int g = 0; g < 4; ++g) {
        float s = bias4[g];
        const int row = g * 4 + ejj;
#pragma unroll
        for (int w = 0; w < 4; ++w)
          s += gx[xb][w][eb][row] + gh[w][eb][row];
        g4[g] = s;
      }
      float fg = 1.f / (1.f + __expf(-g4[0]));
      float ig = 1.f / (1.f + __expf(-g4[1]));
      float gg = 1.f - 2.f / (__expf(2.f * g4[2]) + 1.f);   // tanh, inf-safe
      float og = 1.f / (1.f + __expf(-g4[3]));
      cst  = fg * cst + ig * gg;
      hval = og * (1.f - 2.f / (__expf(2.f * cst) + 1.f));
      hvals[ejj][eb] = hval;
    }
    __syncthreads();

    // ---- phase C: x-waves GEMM x(t+1) while the barrier machinery runs.
    if (!ish && t + 1 < T_) {
      s16_8 af[4][8];
      LD32(af, (unsigned long long)((const char*)xfrag + (size_t)(t + 1) * 131072) + lofs);
      VMWAIT_FENCE;
      f32_4 acc[4];
#pragma unroll
      for (int mt = 0; mt < 4; ++mt) { f32_4 z = {0.f,0.f,0.f,0.f}; acc[mt] = z; }
#pragma unroll
      for (int i = 0; i < 8; ++i)
#pragma unroll
        for (int mt = 0; mt < 4; ++mt)
          acc[mt] = __builtin_amdgcn_mfma_f32_16x16x32_bf16(af[mt][i], wf[i], acc[mt], 0, 0, 0);
#pragma unroll
      for (int mt = 0; mt < 4; ++mt)
#pragma unroll
        for (int r = 0; r < 4; ++r)
          gx[(t + 1) & 1][wv][mt * 16 + (lane >> 4) * 4 + r][lane & 15] = acc[mt][r];
    }
    if (wv == 5) {                       // out store, off the critical chain
      float4 o4 = make_float4(hvals[0][lane], hvals[1][lane],
                              hvals[2][lane], hvals[3][lane]);
      *(float4*)(out + ((size_t)t * 64 + lane) * 1024 + cu * 4) = o4;
    }
    if (t + 1 < T_) {
      if (wv == 4) {                     // publish h (agent-scope -> LLC) + stamp
        float h0 = hvals[0][lane], h1 = hvals[1][lane],
              h2 = hvals[2][lane], h3 = hvals[3][lane];
        unsigned long long pk =
            (unsigned long long)__builtin_bit_cast(unsigned short, (__bf16)h0)
          | ((unsigned long long)__builtin_bit_cast(unsigned short, (__bf16)h1) << 16)
          | ((unsigned long long)__builtin_bit_cast(unsigned short, (__bf16)h2) << 32)
          | ((unsigned long long)__builtin_bit_cast(unsigned short, (__bf16)h3) << 48);
        size_t grpi = ((size_t)(((t + 1) & 1) * 4 + (lane >> 4)) * 32 + (cu >> 3)) * 64
                      + (lane & 15) + 16 * ((cu & 7) >> 1);
        unsigned long long* dst =
            (unsigned long long*)((char*)hfrag + grpi * 16 + (cu & 1) * 8);
        __hip_atomic_store(dst, pk, __ATOMIC_RELAXED, __HIP_MEMORY_SCOPE_AGENT);
        asm volatile("s_waitcnt vmcnt(0)" ::: "memory");   // publishes acked at LLC
        if (lane == 0)
          __hip_atomic_store(stamps + cu, (unsigned)(t + 1), __ATOMIC_RELAXED,
                             __HIP_MEMORY_SCOPE_AGENT);
      }
      if (wv == 6) {                     // direct poll of all 256 stamps
        const unsigned tgt = (unsigned)(t + 1);
        const unsigned int* s0 = stamps + lane;
        bool done;
        do {
          unsigned a = __hip_atomic_load(s0,       __ATOMIC_RELAXED, __HIP_MEMORY_SCOPE_AGENT);
          unsigned b = __hip_atomic_load(s0 + 64,  __ATOMIC_RELAXED, __HIP_MEMORY_SCOPE_AGENT);
          unsigned c = __hip_atomic_load(s0 + 128, __ATOMIC_RELAXED, __HIP_MEMORY_SCOPE_AGENT);
          unsigned d = __hip_atomic_load(s0 + 192, __ATOMIC_RELAXED, __HIP_MEMORY_SCOPE_AGENT);
          done = (a >= tgt) & (b >= tgt) & (c >= tgt) & (d >= tgt);
        } while (!__all(done));
        __builtin_amdgcn_fence(__ATOMIC_ACQUIRE, "agent");   // inv (no wbl2)
      }
    }
    __syncthreads();
  }

  // ---- h_n, c_n
  if (tid >= 256) {
    out[(size_t)T_ * 65536 + (size_t)eb * 1024 + j] = hval;
    out[(size_t)T_ * 65536 + 65536 + (size_t)eb * 1024 + j] = cst;
  }
}

extern "C" void kernel_launch(void* const* d_in, const int* in_sizes, int n_in,
                              void* d_out, int out_size, void* d_ws, size_t ws_size,
                              hipStream_t stream) {
  (void)in_sizes; (void)n_in;
  const float* X  = (const float*)d_in[0];
  const float* Wi = (const float*)d_in[1];
  const float* Wh = (const float*)d_in[2];
  const float* bi = (const float*)d_in[3];
  const float* bh = (const float*)d_in[4];
  float* out = (float*)d_out;

  char* ws = (char*)d_ws;
  const size_t W_BYTES = (size_t)256 * 64 * 64 * 8 * 2;     // 16,777,216
  const size_t H_BYTES = (size_t)2 * 4 * 32 * 64 * 8 * 2;   //    262,144
  const size_t C_BYTES = 4096;
  const size_t X_BYTES = (size_t)512 * 4 * 32 * 64 * 8 * 2; // 67,108,864

  bf16_8* wfrag = (bf16_8*)ws;
  bf16_8* hfrag = (bf16_8*)(ws + W_BYTES);
  unsigned int* ctr = (unsigned int*)(ws + W_BYTES + H_BYTES);

  bf16_8* xfrag;
  if (ws_size >= W_BYTES + H_BYTES + C_BYTES + X_BYTES) {
    xfrag = (bf16_8*)(ws + W_BYTES + H_BYTES + C_BYTES);
  } else {
    // place x-frags in the tail of d_out; out rows clobber xfrag[t'] only for
    // t' < 2t-514 < t+1 (already consumed); final outputs cover everything.
    size_t out_bytes = (size_t)out_size * 4;
    xfrag = (bf16_8*)((char*)d_out + out_bytes - X_BYTES);
  }

  hipMemsetAsync(hfrag, 0, 131072, stream);   // zero h buffer 0 (t=0 reads it)
  hipMemsetAsync(ctr, 0, C_BYTES, stream);    // reset stamp vector

  hipLaunchKernelGGL(p1_xfrag, dim3(16384), dim3(256), 0, stream, X, xfrag);
  hipLaunchKernelGGL(p2_wfrag, dim3(4096), dim3(256), 0, stream, Wi, Wh, wfrag);
  hipLaunchKernelGGL(lstm_persist, dim3(256), dim3(512), 0, stream,
                     bi, bh, (const s16_8*)xfrag, (const s16_8*)wfrag,
                     (s16_8*)hfrag, out, ctr);
}

// Round 10
// 4255.528 us; speedup vs baseline: 1.1067x; 1.1067x over previous
//
#include <hip/hip_runtime.h>
#include <hip/hip_bf16.h>

typedef __bf16  bf16_8 __attribute__((ext_vector_type(8)));
typedef short   s16_8  __attribute__((ext_vector_type(8)));
typedef float   f32_4  __attribute__((ext_vector_type(4)));

#define T_ 512

// Issue 8 global_load_dwordx4 (chunks i=0..7, stride 1024B) from base b0
// (i=0..3) and b0+4096 (i=4..7). Early-clobber: no alias with base regs.
#define LD8(d0,d1,d2,d3,d4,d5,d6,d7, BASE)                                  \
  { unsigned long long _b0 = (BASE), _b1 = (BASE) + 4096ull;                \
    asm volatile(                                                           \
      "global_load_dwordx4 %0, %8, off\n\t"                                 \
      "global_load_dwordx4 %1, %8, off offset:1024\n\t"                     \
      "global_load_dwordx4 %2, %8, off offset:2048\n\t"                     \
      "global_load_dwordx4 %3, %8, off offset:3072\n\t"                     \
      "global_load_dwordx4 %4, %9, off\n\t"                                 \
      "global_load_dwordx4 %5, %9, off offset:1024\n\t"                     \
      "global_load_dwordx4 %6, %9, off offset:2048\n\t"                     \
      "global_load_dwordx4 %7, %9, off offset:3072\n\t"                     \
      : "=&v"(d0),"=&v"(d1),"=&v"(d2),"=&v"(d3),                            \
        "=&v"(d4),"=&v"(d5),"=&v"(d6),"=&v"(d7)                             \
      : "v"(_b0), "v"(_b1)); }

#define LD16(AF, BASE)                                                      \
  LD8(AF[0][0],AF[0][1],AF[0][2],AF[0][3],AF[0][4],AF[0][5],AF[0][6],AF[0][7], (BASE));          \
  LD8(AF[1][0],AF[1][1],AF[1][2],AF[1][3],AF[1][4],AF[1][5],AF[1][6],AF[1][7], (BASE)+32768ull);

// Wait for all loads, then fence the scheduler so no af-consumer (MFMA is
// register-only, NOT ordered by the "memory" clobber) hoists above it.
#define VMWAIT_FENCE                                                        \
  asm volatile("s_waitcnt vmcnt(0)" ::: "memory");                          \
  __builtin_amdgcn_sched_barrier(0)

// ---------------- P1: X fp32 [T][B][1024] -> xfrag bf16 [T][4 mt][32 kc][64 lane][8]
__global__ __launch_bounds__(256) void p1_xfrag(const float* __restrict__ X,
                                                bf16_8* __restrict__ xf) {
  size_t n = (size_t)blockIdx.x * 256 + threadIdx.x;   // 4,194,304 total
  int lane = (int)(n & 63);
  int kc   = (int)((n >> 6) & 31);
  int mt   = (int)((n >> 11) & 3);
  int t    = (int)(n >> 13);
  int b  = 16 * mt + (lane & 15);
  int i0 = 32 * kc + (lane >> 4) * 8;
  const float4* ps = (const float4*)(X + ((size_t)t * 64 + b) * 1024 + i0);
  float4 a = ps[0], c = ps[1];
  bf16_8 v;
  v[0]=(__bf16)a.x; v[1]=(__bf16)a.y; v[2]=(__bf16)a.z; v[3]=(__bf16)a.w;
  v[4]=(__bf16)c.x; v[5]=(__bf16)c.y; v[6]=(__bf16)c.z; v[7]=(__bf16)c.w;
  xf[n] = v;
}

// ---------------- P2: Wi,Wh fp32 -> wfrag bf16 [256 cu][64 kc][64 lane][8]
__global__ __launch_bounds__(256) void p2_wfrag(const float* __restrict__ Wi,
                                                const float* __restrict__ Wh,
                                                bf16_8* __restrict__ wf) {
  size_t n = (size_t)blockIdx.x * 256 + threadIdx.x;   // 1,048,576 total
  int lane = (int)(n & 63);
  int kc   = (int)((n >> 6) & 63);
  int cu   = (int)(n >> 12);
  int n16 = lane & 15;
  int g  = n16 >> 2;
  int jj = n16 & 3;
  int col = 4 * cu + jj;
  int k = 32 * kc + (lane >> 4) * 8;
  const float* src = (k < 1024)
      ? (Wi + ((size_t)g * 1024 + col) * 1024 + k)
      : (Wh + ((size_t)g * 1024 + col) * 1024 + (k - 1024));
  const float4* ps = (const float4*)src;
  float4 a = ps[0], c = ps[1];
  bf16_8 v;
  v[0]=(__bf16)a.x; v[1]=(__bf16)a.y; v[2]=(__bf16)a.z; v[3]=(__bf16)a.w;
  v[4]=(__bf16)c.x; v[5]=(__bf16)c.y; v[6]=(__bf16)c.z; v[7]=(__bf16)c.w;
  wf[n] = v;
}

// ---------------- persistent LSTM, half-batch pipelined: 256 blocks x 512 thr
// Iteration k: half S=k&1, step t=k>>1. h_S(t) published at iter k, consumed
// at iter k+2 -> certification rides one iteration behind, off critical path:
//   arrivals: phase C of k (wave4, after sc1 publish acked)
//   certify:  block0 wave6, phase B of k+1 (poll 8 group ctrs -> flag=k)
//   observe:  all wave6, phase C of k+1 (flag already set) + acquire fence
//   consume:  phase A of k+2 (h-waves load fresh h via invalidated caches)
__global__ __launch_bounds__(512, 2) void lstm_persist(
    const float* __restrict__ bi, const float* __restrict__ bh,
    const s16_8* __restrict__ xfrag, const s16_8* __restrict__ wfrag,
    s16_8* __restrict__ hfrag, float* __restrict__ out,
    unsigned int* __restrict__ ctr)
{
  __shared__ float gx[2][2][4][32][17];  // [half][slot][wave][b][row] 69,632 B
  __shared__ float gh[4][32][17];        //                            8,704 B
  __shared__ float hvals[4][32];         //                              512 B

  const int tid  = threadIdx.x;
  const int cu   = blockIdx.x;
  const int wv   = tid >> 6;
  const int lane = tid & 63;
  const bool ish = (wv >= 4);
  const unsigned long long lofs = (unsigned long long)(((wv & 3) * 8) * 1024 + lane * 16);

  // resident B-fragments of W: 16 rows (4 cols x 4 gates) per CU
  s16_8 wf[8];
#pragma unroll
  for (int i = 0; i < 8; ++i)
    wf[i] = wfrag[((size_t)cu * 64 + wv * 8 + i) * 64 + lane];
#pragma unroll
  for (int i = 0; i < 8; ++i)
    asm volatile("" : "+v"(wf[i]));

  // cell identity: threads 256..383 (waves 4,5): eb = batch-in-half, ejj = col
  const int et  = tid - 256;
  const int eb  = et & 31;
  const int ejj = (et >> 5) & 3;
  const int j   = cu * 4 + ejj;
  const bool iscell = (tid >= 256 && tid < 384);
  float bias4[4] = {0.f, 0.f, 0.f, 0.f};
  if (iscell) {
#pragma unroll
    for (int g = 0; g < 4; ++g) bias4[g] = bi[g * 1024 + j] + bh[g * 1024 + j];
  }
  float cstA = 0.f, hvalA = 0.f, cstB = 0.f, hvalB = 0.f;

  unsigned int* flag = ctr + 2048;   // byte 8192, own line

  // ---- prologue: x-waves compute gx for t=0, both halves (slot 0)
  if (!ish) {
#pragma unroll
    for (int S = 0; S < 2; ++S) {
      s16_8 af[2][8];
      unsigned long long xb = (unsigned long long)(const char*)xfrag
                              + (unsigned)(S * 65536) + lofs;
      LD16(af, xb);
      VMWAIT_FENCE;
      f32_4 a0 = {0.f,0.f,0.f,0.f}, a1 = {0.f,0.f,0.f,0.f};
#pragma unroll
      for (int c = 0; c < 8; ++c) {
        a0 = __builtin_amdgcn_mfma_f32_16x16x32_bf16(af[0][c], wf[c], a0, 0, 0, 0);
        a1 = __builtin_amdgcn_mfma_f32_16x16x32_bf16(af[1][c], wf[c], a1, 0, 0, 0);
      }
#pragma unroll
      for (int r = 0; r < 4; ++r) {
        gx[S][0][wv][(lane >> 4) * 4 + r][lane & 15]      = a0[r];
        gx[S][0][wv][16 + (lane >> 4) * 4 + r][lane & 15] = a1[r];
      }
    }
  }
  __syncthreads();

#define STEP(S, CST, HVAL) {                                                 \
    const int k = 2 * t + (S);                                               \
    /* ---- phase A: h-waves h-GEMM (S,t); x-waves x-GEMM (S,t+1) ---- */    \
    if (ish) {                                                               \
      s16_8 af[2][8];                                                        \
      unsigned long long hb = (unsigned long long)(const char*)hfrag         \
          + (unsigned)((((t) & 1) ^ 1) * 131072 + (S) * 65536) + lofs;       \
      LD16(af, hb);                                                          \
      VMWAIT_FENCE;                                                          \
      f32_4 a0 = {0.f,0.f,0.f,0.f}, a1 = {0.f,0.f,0.f,0.f};                  \
      _Pragma("unroll")                                                      \
      for (int c = 0; c < 8; ++c) {                                          \
        a0 = __builtin_amdgcn_mfma_f32_16x16x32_bf16(af[0][c], wf[c], a0, 0, 0, 0); \
        a1 = __builtin_amdgcn_mfma_f32_16x16x32_bf16(af[1][c], wf[c], a1, 0, 0, 0); \
      }                                                                      \
      _Pragma("unroll")                                                      \
      for (int r = 0; r < 4; ++r) {                                          \
        gh[wv & 3][(lane >> 4) * 4 + r][lane & 15]      = a0[r];             \
        gh[wv & 3][16 + (lane >> 4) * 4 + r][lane & 15] = a1[r];             \
      }                                                                      \
    } else if (t + 1 < T_) {                                                 \
      s16_8 af[2][8];                                                        \
      unsigned long long xb = (unsigned long long)(const char*)xfrag         \
          + (size_t)(t + 1) * 131072 + (unsigned)((S) * 65536) + lofs;       \
      LD16(af, xb);                                                          \
      VMWAIT_FENCE;                                                          \
      f32_4 a0 = {0.f,0.f,0.f,0.f}, a1 = {0.f,0.f,0.f,0.f};                  \
      _Pragma("unroll")                                                      \
      for (int c = 0; c < 8; ++c) {                                          \
        a0 = __builtin_amdgcn_mfma_f32_16x16x32_bf16(af[0][c], wf[c], a0, 0, 0, 0); \
        a1 = __builtin_amdgcn_mfma_f32_16x16x32_bf16(af[1][c], wf[c], a1, 0, 0, 0); \
      }                                                                      \
      _Pragma("unroll")                                                      \
      for (int r = 0; r < 4; ++r) {                                          \
        gx[S][(t + 1) & 1][wv][(lane >> 4) * 4 + r][lane & 15]      = a0[r]; \
        gx[S][(t + 1) & 1][wv][16 + (lane >> 4) * 4 + r][lane & 15] = a1[r]; \
      }                                                                      \
    }                                                                        \
    __syncthreads();                                                         \
    /* ---- phase B: cell update (waves 4,5) + block0 certify (wave6) ---- */\
    if (iscell) {                                                            \
      float g4[4];                                                           \
      _Pragma("unroll")                                                      \
      for (int g = 0; g < 4; ++g) {                                          \
        const int row = g * 4 + ejj;                                         \
        float sa = bias4[g];                                                 \
        _Pragma("unroll")                                                    \
        for (int w = 0; w < 4; ++w)                                          \
          sa += gx[S][(t) & 1][w][eb][row] + gh[w][eb][row];                 \
        g4[g] = sa;                                                          \
      }                                                                      \
      float fg = 1.f / (1.f + __expf(-g4[0]));                               \
      float ig = 1.f / (1.f + __expf(-g4[1]));                               \
      float gg = 1.f - 2.f / (__expf(2.f * g4[2]) + 1.f);                    \
      float og = 1.f / (1.f + __expf(-g4[3]));                               \
      CST  = fg * CST + ig * gg;                                             \
      HVAL = og * (1.f - 2.f / (__expf(2.f * CST) + 1.f));                   \
      hvals[ejj][eb] = HVAL;                                                 \
    }                                                                        \
    if (wv == 6 && cu == 0 && k >= 1 && k <= 1022) {                         \
      const unsigned tgt = 32u * (unsigned)((((k) - 1) >> 2) + 1);           \
      const int slot = ((k) - 1) & 3;                                        \
      if (lane < 8) {                                                        \
        unsigned int* cc = ctr + (slot * 8 + lane) * 64;                     \
        while (__hip_atomic_load(cc, __ATOMIC_RELAXED, __HIP_MEMORY_SCOPE_AGENT) < tgt) {} \
      }                                                                      \
      if (lane == 0)                                                         \
        __hip_atomic_store(flag, (unsigned)(k), __ATOMIC_RELAXED,            \
                           __HIP_MEMORY_SCOPE_AGENT);                        \
    }                                                                        \
    __syncthreads();                                                         \
    /* ---- phase C: publish + arrive (w4), out (w5), flag+fence (w6) ---- */\
    if (wv == 5 && lane < 32) {                                              \
      float4 o4 = make_float4(hvals[0][lane], hvals[1][lane],                \
                              hvals[2][lane], hvals[3][lane]);               \
      *(float4*)(out + ((size_t)(t) * 64 + (S) * 32 + lane) * 1024 + cu * 4) = o4; \
    }                                                                        \
    if (wv == 4 && k <= 1021) {                                              \
      if (lane < 32) {                                                       \
        float h0 = hvals[0][lane], h1 = hvals[1][lane],                      \
              h2 = hvals[2][lane], h3 = hvals[3][lane];                      \
        unsigned long long pk =                                              \
            (unsigned long long)__builtin_bit_cast(unsigned short, (__bf16)h0)        \
          | ((unsigned long long)__builtin_bit_cast(unsigned short, (__bf16)h1) << 16)\
          | ((unsigned long long)__builtin_bit_cast(unsigned short, (__bf16)h2) << 32)\
          | ((unsigned long long)__builtin_bit_cast(unsigned short, (__bf16)h3) << 48);\
        char* hbp = (char*)hfrag + (unsigned)(((t) & 1) * 131072 + (S) * 65536);      \
        size_t grpi = ((size_t)(lane >> 4) * 32 + (cu >> 3)) * 64            \
                      + (lane & 15) + 16 * ((cu & 7) >> 1);                  \
        __hip_atomic_store((unsigned long long*)(hbp + grpi * 16 + (cu & 1) * 8), pk, \
                           __ATOMIC_RELAXED, __HIP_MEMORY_SCOPE_AGENT);      \
      }                                                                      \
      asm volatile("s_waitcnt vmcnt(0)" ::: "memory");                       \
      if (lane == 0)                                                         \
        atomicAdd(ctr + (((k) & 3) * 8 + (cu >> 5)) * 64, 1u);               \
    }                                                                        \
    if (wv == 6 && k >= 1 && k <= 1022) {                                    \
      if (lane == 0)                                                         \
        while (__hip_atomic_load(flag, __ATOMIC_RELAXED, __HIP_MEMORY_SCOPE_AGENT)    \
               < (unsigned)(k)) {}                                           \
      __builtin_amdgcn_fence(__ATOMIC_ACQUIRE, "agent");                     \
    }                                                                        \
    __syncthreads();                                                         \
  }

  for (int t = 0; t < T_; ++t) {
    STEP(0, cstA, hvalA)
    STEP(1, cstB, hvalB)
  }
#undef STEP

  // ---- h_n, c_n (both halves)
  if (iscell) {
    out[(size_t)T_ * 65536 + (size_t)eb * 1024 + j]        = hvalA;
    out[(size_t)T_ * 65536 + (size_t)(32 + eb) * 1024 + j] = hvalB;
    out[(size_t)T_ * 65536 + 65536 + (size_t)eb * 1024 + j]        = cstA;
    out[(size_t)T_ * 65536 + 65536 + (size_t)(32 + eb) * 1024 + j] = cstB;
  }
}

extern "C" void kernel_launch(void* const* d_in, const int* in_sizes, int n_in,
                              void* d_out, int out_size, void* d_ws, size_t ws_size,
                              hipStream_t stream) {
  (void)in_sizes; (void)n_in;
  const float* X  = (const float*)d_in[0];
  const float* Wi = (const float*)d_in[1];
  const float* Wh = (const float*)d_in[2];
  const float* bi = (const float*)d_in[3];
  const float* bh = (const float*)d_in[4];
  float* out = (float*)d_out;

  char* ws = (char*)d_ws;
  const size_t W_BYTES = (size_t)256 * 64 * 64 * 8 * 2;     // 16,777,216
  const size_t H_BYTES = (size_t)2 * 2 * 65536;             //    262,144
  const size_t C_BYTES = 16384;
  const size_t X_BYTES = (size_t)512 * 4 * 32 * 64 * 8 * 2; // 67,108,864

  bf16_8* wfrag = (bf16_8*)ws;
  bf16_8* hfrag = (bf16_8*)(ws + W_BYTES);
  unsigned int* ctr = (unsigned int*)(ws + W_BYTES + H_BYTES);

  bf16_8* xfrag;
  if (ws_size >= W_BYTES + H_BYTES + C_BYTES + X_BYTES) {
    xfrag = (bf16_8*)(ws + W_BYTES + H_BYTES + C_BYTES);
  } else {
    // place x-frags in the tail of d_out; out rows clobber xfrag[t'] only for
    // t' < 2t-514 < t+1 (already consumed); final outputs cover everything.
    size_t out_bytes = (size_t)out_size * 4;
    xfrag = (bf16_8*)((char*)d_out + out_bytes - X_BYTES);
  }

  // zero h slot-1 region (both halves read it at t=0) + counters/flag
  hipMemsetAsync((char*)hfrag + 131072, 0, 131072, stream);
  hipMemsetAsync(ctr, 0, C_BYTES, stream);

  hipLaunchKernelGGL(p1_xfrag, dim3(16384), dim3(256), 0, stream, X, xfrag);
  hipLaunchKernelGGL(p2_wfrag, dim3(4096), dim3(256), 0, stream, Wi, Wh, wfrag);
  hipLaunchKernelGGL(lstm_persist, dim3(256), dim3(512), 0, stream,
                     bi, bh, (const s16_8*)xfrag, (const s16_8*)wfrag,
                     (s16_8*)hfrag, out, ctr);
}

// Round 11
// 2662.663 us; speedup vs baseline: 1.7687x; 1.5982x over previous
//
#include <hip/hip_runtime.h>
#include <hip/hip_bf16.h>

typedef __bf16  bf16_8 __attribute__((ext_vector_type(8)));
typedef short   s16_8  __attribute__((ext_vector_type(8)));
typedef float   f32_4  __attribute__((ext_vector_type(4)));

#define T_ 512

// Issue 8 global_load_dwordx4 (one mt group: frag i=0..7, stride 1024B) from
// base b0 (i=0..3) and b0+4096 (i=4..7). No wait — caller waits via VMWAIT.
// Early-clobber outputs: must not alias the base-address registers.
#define LD8(d0,d1,d2,d3,d4,d5,d6,d7, BASE)                                  \
  { unsigned long long _b0 = (BASE), _b1 = (BASE) + 4096ull;                \
    asm volatile(                                                           \
      "global_load_dwordx4 %0, %8, off\n\t"                                 \
      "global_load_dwordx4 %1, %8, off offset:1024\n\t"                     \
      "global_load_dwordx4 %2, %8, off offset:2048\n\t"                     \
      "global_load_dwordx4 %3, %8, off offset:3072\n\t"                     \
      "global_load_dwordx4 %4, %9, off\n\t"                                 \
      "global_load_dwordx4 %5, %9, off offset:1024\n\t"                     \
      "global_load_dwordx4 %6, %9, off offset:2048\n\t"                     \
      "global_load_dwordx4 %7, %9, off offset:3072\n\t"                     \
      : "=&v"(d0),"=&v"(d1),"=&v"(d2),"=&v"(d3),                            \
        "=&v"(d4),"=&v"(d5),"=&v"(d6),"=&v"(d7)                             \
      : "v"(_b0), "v"(_b1)); }

// Coherent variant for h: sc0 sc1 = bypass L1/L2, read at LLC (the coherence
// point where the sc1 publishes land). Makes the acquire fence unnecessary.
#define LD8C(d0,d1,d2,d3,d4,d5,d6,d7, BASE)                                 \
  { unsigned long long _b0 = (BASE), _b1 = (BASE) + 4096ull;                \
    asm volatile(                                                           \
      "global_load_dwordx4 %0, %8, off sc0 sc1\n\t"                         \
      "global_load_dwordx4 %1, %8, off offset:1024 sc0 sc1\n\t"             \
      "global_load_dwordx4 %2, %8, off offset:2048 sc0 sc1\n\t"             \
      "global_load_dwordx4 %3, %8, off offset:3072 sc0 sc1\n\t"             \
      "global_load_dwordx4 %4, %9, off sc0 sc1\n\t"                         \
      "global_load_dwordx4 %5, %9, off offset:1024 sc0 sc1\n\t"             \
      "global_load_dwordx4 %6, %9, off offset:2048 sc0 sc1\n\t"             \
      "global_load_dwordx4 %7, %9, off offset:3072 sc0 sc1\n\t"             \
      : "=&v"(d0),"=&v"(d1),"=&v"(d2),"=&v"(d3),                            \
        "=&v"(d4),"=&v"(d5),"=&v"(d6),"=&v"(d7)                             \
      : "v"(_b0), "v"(_b1)); }

#define LD32(AF, BASE)                                                      \
  LD8(AF[0][0],AF[0][1],AF[0][2],AF[0][3],AF[0][4],AF[0][5],AF[0][6],AF[0][7], (BASE));          \
  LD8(AF[1][0],AF[1][1],AF[1][2],AF[1][3],AF[1][4],AF[1][5],AF[1][6],AF[1][7], (BASE)+32768ull); \
  LD8(AF[2][0],AF[2][1],AF[2][2],AF[2][3],AF[2][4],AF[2][5],AF[2][6],AF[2][7], (BASE)+65536ull); \
  LD8(AF[3][0],AF[3][1],AF[3][2],AF[3][3],AF[3][4],AF[3][5],AF[3][6],AF[3][7], (BASE)+98304ull);

#define LD32C(AF, BASE)                                                     \
  LD8C(AF[0][0],AF[0][1],AF[0][2],AF[0][3],AF[0][4],AF[0][5],AF[0][6],AF[0][7], (BASE));          \
  LD8C(AF[1][0],AF[1][1],AF[1][2],AF[1][3],AF[1][4],AF[1][5],AF[1][6],AF[1][7], (BASE)+32768ull); \
  LD8C(AF[2][0],AF[2][1],AF[2][2],AF[2][3],AF[2][4],AF[2][5],AF[2][6],AF[2][7], (BASE)+65536ull); \
  LD8C(AF[3][0],AF[3][1],AF[3][2],AF[3][3],AF[3][4],AF[3][5],AF[3][6],AF[3][7], (BASE)+98304ull);

// Wait for all loads, then fence the scheduler so no af-consumer (MFMA is
// register-only, NOT ordered by the "memory" clobber) hoists above it.
#define VMWAIT_FENCE                                                        \
  asm volatile("s_waitcnt vmcnt(0)" ::: "memory");                          \
  __builtin_amdgcn_sched_barrier(0)

// ---------------- P1: X fp32 [T][B][1024] -> xfrag bf16 [T][4 mt][32 kc][64 lane][8]
__global__ __launch_bounds__(256) void p1_xfrag(const float* __restrict__ X,
                                                bf16_8* __restrict__ xf) {
  size_t n = (size_t)blockIdx.x * 256 + threadIdx.x;   // 4,194,304 total
  int lane = (int)(n & 63);
  int kc   = (int)((n >> 6) & 31);
  int mt   = (int)((n >> 11) & 3);
  int t    = (int)(n >> 13);
  int b  = 16 * mt + (lane & 15);
  int i0 = 32 * kc + (lane >> 4) * 8;
  const float4* ps = (const float4*)(X + ((size_t)t * 64 + b) * 1024 + i0);
  float4 a = ps[0], c = ps[1];
  bf16_8 v;
  v[0]=(__bf16)a.x; v[1]=(__bf16)a.y; v[2]=(__bf16)a.z; v[3]=(__bf16)a.w;
  v[4]=(__bf16)c.x; v[5]=(__bf16)c.y; v[6]=(__bf16)c.z; v[7]=(__bf16)c.w;
  xf[n] = v;
}

// ---------------- P2: Wi,Wh fp32 -> wfrag bf16 [256 cu][64 kc][64 lane][8]
__global__ __launch_bounds__(256) void p2_wfrag(const float* __restrict__ Wi,
                                                const float* __restrict__ Wh,
                                                bf16_8* __restrict__ wf) {
  size_t n = (size_t)blockIdx.x * 256 + threadIdx.x;   // 1,048,576 total
  int lane = (int)(n & 63);
  int kc   = (int)((n >> 6) & 63);
  int cu   = (int)(n >> 12);
  int n16 = lane & 15;
  int g  = n16 >> 2;
  int jj = n16 & 3;
  int col = 4 * cu + jj;
  int k = 32 * kc + (lane >> 4) * 8;
  const float* src = (k < 1024)
      ? (Wi + ((size_t)g * 1024 + col) * 1024 + k)
      : (Wh + ((size_t)g * 1024 + col) * 1024 + (k - 1024));
  const float4* ps = (const float4*)src;
  float4 a = ps[0], c = ps[1];
  bf16_8 v;
  v[0]=(__bf16)a.x; v[1]=(__bf16)a.y; v[2]=(__bf16)a.z; v[3]=(__bf16)a.w;
  v[4]=(__bf16)c.x; v[5]=(__bf16)c.y; v[6]=(__bf16)c.z; v[7]=(__bf16)c.w;
  wf[n] = v;
}

// ---------------- persistent LSTM: 256 blocks x 512 threads (8 waves)
// Phase A: h-waves (4-7) h-GEMM(t) via sc0/sc1 LLC-direct loads (coherent
//          with the sc1 publishes -> NO acquire fence, L2 never invalidated).
// Phase B: elementwise on h-waves.
// Phase C: x-waves (0-3) x-GEMM(t+1) from warm L2; wave4 publish+arrive;
//          wave6 relay barrier (block0 certifies 8 group ctrs -> flag).
__global__ __launch_bounds__(512, 2) void lstm_persist(
    const float* __restrict__ bi, const float* __restrict__ bh,
    const s16_8* __restrict__ xfrag, const s16_8* __restrict__ wfrag,
    s16_8* __restrict__ hfrag, float* __restrict__ out,
    unsigned int* __restrict__ ctr)
{
  __shared__ float gx[2][4][64][17];   // x-partials, double-buffered  34,816 B
  __shared__ float gh[4][64][17];      // h-partials                   17,408 B
  __shared__ float hvals[4][64];       // h gather for pack             1,024 B

  const int tid  = threadIdx.x;
  const int cu   = blockIdx.x;
  const int wv   = tid >> 6;
  const int lane = tid & 63;
  const bool ish = (wv >= 4);
  const unsigned long long lofs = (unsigned long long)(((wv & 3) * 8) * 1024 + lane * 16);

  // resident B-fragments of W (registers): 16 rows (4 cols x 4 gates) per CU
  s16_8 wf[8];
#pragma unroll
  for (int i = 0; i < 8; ++i)
    wf[i] = wfrag[((size_t)cu * 64 + wv * 8 + i) * 64 + lane];
#pragma unroll
  for (int i = 0; i < 8; ++i)
    asm volatile("" : "+v"(wf[i]));    // pin resident: no remat/re-load per step

  // elementwise identity (threads 256..511): eb = batch, ejj = column-in-block
  const int et  = tid - 256;
  const int eb  = et & 63;
  const int ejj = (et >> 6) & 3;
  const int j   = cu * 4 + ejj;
  float bias4[4] = {0.f, 0.f, 0.f, 0.f};
  if (tid >= 256) {
#pragma unroll
    for (int g = 0; g < 4; ++g) bias4[g] = bi[g * 1024 + j] + bh[g * 1024 + j];
  }
  float cst = 0.f, hval = 0.f;

  unsigned int* grp  = ctr + (cu >> 5) * 64;   // 8 group counters, 256 B apart
  unsigned int* flag = ctr + 512;              // release flag, own line

  // ---- prologue: x-waves compute gx(0)
  if (!ish) {
    s16_8 af[4][8];
    LD32(af, (unsigned long long)(const char*)xfrag + lofs);
    VMWAIT_FENCE;
    f32_4 acc[4];
#pragma unroll
    for (int mt = 0; mt < 4; ++mt) { f32_4 z = {0.f,0.f,0.f,0.f}; acc[mt] = z; }
#pragma unroll
    for (int i = 0; i < 8; ++i)
#pragma unroll
      for (int mt = 0; mt < 4; ++mt)
        acc[mt] = __builtin_amdgcn_mfma_f32_16x16x32_bf16(af[mt][i], wf[i], acc[mt], 0, 0, 0);
#pragma unroll
    for (int mt = 0; mt < 4; ++mt)
#pragma unroll
      for (int r = 0; r < 4; ++r)
        gx[0][wv][mt * 16 + (lane >> 4) * 4 + r][lane & 15] = acc[mt][r];
  }
  __syncthreads();

  for (int t = 0; t < T_; ++t) {
    // ---- phase A: h-waves GEMM h(t-1); loads go LLC-direct (sc0 sc1),
    //      coherent with last step's publishes without any cache inv.
    if (ish) {
      s16_8 af[4][8];
      LD32C(af, (unsigned long long)((const char*)hfrag + (size_t)(t & 1) * 131072) + lofs);
      VMWAIT_FENCE;
      f32_4 acc[4];
#pragma unroll
      for (int mt = 0; mt < 4; ++mt) { f32_4 z = {0.f,0.f,0.f,0.f}; acc[mt] = z; }
#pragma unroll
      for (int i = 0; i < 8; ++i)
#pragma unroll
        for (int mt = 0; mt < 4; ++mt)
          acc[mt] = __builtin_amdgcn_mfma_f32_16x16x32_bf16(af[mt][i], wf[i], acc[mt], 0, 0, 0);
#pragma unroll
      for (int mt = 0; mt < 4; ++mt)
#pragma unroll
        for (int r = 0; r < 4; ++r)
          gh[wv & 3][mt * 16 + (lane >> 4) * 4 + r][lane & 15] = acc[mt][r];
    }
    __syncthreads();

    // ---- phase B: elementwise cell update on h-waves (threads 256..511)
    if (tid >= 256) {
      const int xb = t & 1;
      float g4[4];
#pragma unroll
      for (int g = 0; g < 4; ++g) {
        float s = bias4[g];
        const int row = g * 4 + ejj;
#pragma unroll
        for (int w = 0; w < 4; ++w)
          s += gx[xb][w][eb][row] + gh[w][eb][row];
        g4[g] = s;
      }
      float fg = 1.f / (1.f + __expf(-g4[0]));
      float ig = 1.f / (1.f + __expf(-g4[1]));
      float gg = 1.f - 2.f / (__expf(2.f * g4[2]) + 1.f);   // tanh, inf-safe
      float og = 1.f / (1.f + __expf(-g4[3]));
      cst  = fg * cst + ig * gg;
      hval = og * (1.f - 2.f / (__expf(2.f * cst) + 1.f));
      hvals[ejj][eb] = hval;
    }
    __syncthreads();

    // ---- phase C: x-waves GEMM x(t+1) from warm L2 (never invalidated);
    //      wave4 publishes h + arrives; wave6 runs the relay barrier.
    if (!ish && t + 1 < T_) {
      s16_8 af[4][8];
      LD32(af, (unsigned long long)((const char*)xfrag + (size_t)(t + 1) * 131072) + lofs);
      VMWAIT_FENCE;
      f32_4 acc[4];
#pragma unroll
      for (int mt = 0; mt < 4; ++mt) { f32_4 z = {0.f,0.f,0.f,0.f}; acc[mt] = z; }
#pragma unroll
      for (int i = 0; i < 8; ++i)
#pragma unroll
        for (int mt = 0; mt < 4; ++mt)
          acc[mt] = __builtin_amdgcn_mfma_f32_16x16x32_bf16(af[mt][i], wf[i], acc[mt], 0, 0, 0);
#pragma unroll
      for (int mt = 0; mt < 4; ++mt)
#pragma unroll
        for (int r = 0; r < 4; ++r)
          gx[(t + 1) & 1][wv][mt * 16 + (lane >> 4) * 4 + r][lane & 15] = acc[mt][r];
    }
    if (wv == 5) {                       // out store, off the critical chain
      float4 o4 = make_float4(hvals[0][lane], hvals[1][lane],
                              hvals[2][lane], hvals[3][lane]);
      *(float4*)(out + ((size_t)t * 64 + lane) * 1024 + cu * 4) = o4;
    }
    if (t + 1 < T_) {
      if (wv == 4) {                     // publish h (agent-scope -> LLC) + arrive
        float h0 = hvals[0][lane], h1 = hvals[1][lane],
              h2 = hvals[2][lane], h3 = hvals[3][lane];
        unsigned long long pk =
            (unsigned long long)__builtin_bit_cast(unsigned short, (__bf16)h0)
          | ((unsigned long long)__builtin_bit_cast(unsigned short, (__bf16)h1) << 16)
          | ((unsigned long long)__builtin_bit_cast(unsigned short, (__bf16)h2) << 32)
          | ((unsigned long long)__builtin_bit_cast(unsigned short, (__bf16)h3) << 48);
        size_t grpi = ((size_t)(((t + 1) & 1) * 4 + (lane >> 4)) * 32 + (cu >> 3)) * 64
                      + (lane & 15) + 16 * ((cu & 7) >> 1);
        unsigned long long* dst =
            (unsigned long long*)((char*)hfrag + grpi * 16 + (cu & 1) * 8);
        __hip_atomic_store(dst, pk, __ATOMIC_RELAXED, __HIP_MEMORY_SCOPE_AGENT);
        asm volatile("s_waitcnt vmcnt(0)" ::: "memory");   // acked at LLC
        if (lane == 0) atomicAdd(grp, 1u);
      }
      if (wv == 6) {                     // relay barrier (no fence needed)
        const unsigned tgt = 32u * (unsigned)(t + 1);
        if (cu == 0) {
          if (lane < 8) {
            unsigned int* c = ctr + lane * 64;
            while (__hip_atomic_load(c, __ATOMIC_RELAXED, __HIP_MEMORY_SCOPE_AGENT) < tgt)
              __builtin_amdgcn_s_sleep(1);
          }
          if (lane == 0)
            __hip_atomic_store(flag, (unsigned)(t + 1), __ATOMIC_RELAXED,
                               __HIP_MEMORY_SCOPE_AGENT);
        } else if (lane == 0) {
          while (__hip_atomic_load(flag, __ATOMIC_RELAXED, __HIP_MEMORY_SCOPE_AGENT)
                 < (unsigned)(t + 1))
            __builtin_amdgcn_s_sleep(1);
        }
      }
    }
    __syncthreads();
  }

  // ---- h_n, c_n
  if (tid >= 256) {
    out[(size_t)T_ * 65536 + (size_t)eb * 1024 + j] = hval;
    out[(size_t)T_ * 65536 + 65536 + (size_t)eb * 1024 + j] = cst;
  }
}

extern "C" void kernel_launch(void* const* d_in, const int* in_sizes, int n_in,
                              void* d_out, int out_size, void* d_ws, size_t ws_size,
                              hipStream_t stream) {
  (void)in_sizes; (void)n_in;
  const float* X  = (const float*)d_in[0];
  const float* Wi = (const float*)d_in[1];
  const float* Wh = (const float*)d_in[2];
  const float* bi = (const float*)d_in[3];
  const float* bh = (const float*)d_in[4];
  float* out = (float*)d_out;

  char* ws = (char*)d_ws;
  const size_t W_BYTES = (size_t)256 * 64 * 64 * 8 * 2;     // 16,777,216
  const size_t H_BYTES = (size_t)2 * 4 * 32 * 64 * 8 * 2;   //    262,144
  const size_t C_BYTES = 4096;
  const size_t X_BYTES = (size_t)512 * 4 * 32 * 64 * 8 * 2; // 67,108,864

  bf16_8* wfrag = (bf16_8*)ws;
  bf16_8* hfrag = (bf16_8*)(ws + W_BYTES);
  unsigned int* ctr = (unsigned int*)(ws + W_BYTES + H_BYTES);

  bf16_8* xfrag;
  if (ws_size >= W_BYTES + H_BYTES + C_BYTES + X_BYTES) {
    xfrag = (bf16_8*)(ws + W_BYTES + H_BYTES + C_BYTES);
  } else {
    // place x-frags in the tail of d_out; out rows clobber xfrag[t'] only for
    // t' < 2t-514 < t+1 (already consumed); final outputs cover everything.
    size_t out_bytes = (size_t)out_size * 4;
    xfrag = (bf16_8*)((char*)d_out + out_bytes - X_BYTES);
  }

  hipMemsetAsync(hfrag, 0, 131072, stream);   // zero h buffer 0 (t=0 reads it)
  hipMemsetAsync(ctr, 0, C_BYTES, stream);    // reset barrier counters + flag

  hipLaunchKernelGGL(p1_xfrag, dim3(16384), dim3(256), 0, stream, X, xfrag);
  hipLaunchKernelGGL(p2_wfrag, dim3(4096), dim3(256), 0, stream, Wi, Wh, wfrag);
  hipLaunchKernelGGL(lstm_persist, dim3(256), dim3(512), 0, stream,
                     bi, bh, (const s16_8*)xfrag, (const s16_8*)wfrag,
                     (s16_8*)hfrag, out, ctr);
}